// Round 3
// baseline (269.606 us; speedup 1.0000x reference)
//
#include <hip/hip_runtime.h>

// FNet 2D FFT real part: x[8][4096][768] fp32 -> Re(FFT2 over (seq, hidden)).
//
// ws layout (float2, 8*384*4096 = 100.66 MB exactly):
//   plane k2 in [1,383]: ws[b][k2][n1] = Y1[n1][k2]  (hidden-FFT output, transposed)
//   plane 0 packs the two REAL planes: ws[b][0][n1] = (Y1[n1][0], Y1[n1][384])
// Pass 2 FFTs each plane over n1 (4096), writes Re in place over the row's
// first half (row pitch 2*4096 floats). Plane-0 block recovers both real
// spectra (two-real-FFTs-in-one trick) into halves [0,4096) and [4096,8192).
// Pass 3 transposes + Hermitian-mirrors: out[k1][k2]=v, out[-k1][768-k2]=v.

constexpr int HN = 768;
constexpr int SN = 4096;
constexpr int KP = 384;
constexpr float PI2 = 6.283185307179586f;

static __device__ __forceinline__ float2 cadd(float2 a, float2 b) { return make_float2(a.x + b.x, a.y + b.y); }
static __device__ __forceinline__ float2 csub(float2 a, float2 b) { return make_float2(a.x - b.x, a.y - b.y); }
static __device__ __forceinline__ float2 cmul(float2 a, float2 b) { return make_float2(a.x * b.x - a.y * b.y, a.x * b.y + a.y * b.x); }

static __device__ __forceinline__ void bfly4(float2 v0, float2 v1, float2 v2, float2 v3,
                                             float2& V0, float2& V1, float2& V2, float2& V3) {
  float2 t0 = cadd(v0, v2), t1 = csub(v0, v2);
  float2 t2 = cadd(v1, v3), t3 = csub(v1, v3);
  float2 t3i = make_float2(t3.y, -t3.x);   // -i * t3
  V0 = cadd(t0, t2); V2 = csub(t0, t2);
  V1 = cadd(t1, t3i); V3 = csub(t1, t3i);
}

// ---------------- Pass 1: hidden FFT (768 = 3*4^4), 4 complex rows = 8 real rows, in-place LDS ----------------
__global__ __launch_bounds__(256, 6)
void fft_hidden(const float* __restrict__ x, float2* __restrict__ ws) {
  __shared__ float2 buf[4 * HN];   // 24 KB
  __shared__ float2 T768[192];     // 1.5 KB twiddle table
  const int tid = threadIdx.x;
  const int blk = blockIdx.x;      // 4096 blocks
  const int b = blk & 7;           // batch pinned per XCD
  const int n0 = (blk >> 3) * 8;   // first of 8 real rows

  for (int r = tid; r < 192; r += 256) {
    float s, c; __sincosf(-PI2 * (float)r * (1.0f / 768.0f), &s, &c);
    T768[r] = make_float2(c, s);
  }

  // Load 8 real rows packed as 4 complex rows: z_p[n] = x[n0+2p][n] + i x[n0+2p+1][n]
  const float4* xb4 = (const float4*)(x + (size_t)b * SN * HN);
  for (int f = tid; f < 768; f += 256) {      // 3 exact iterations
    const int p = f / 192;
    const int q = f - p * 192;
    float4 va = xb4[(size_t)(n0 + 2 * p) * 192 + q];
    float4 vb = xb4[(size_t)(n0 + 2 * p + 1) * 192 + q];
    float2* d = buf + p * HN + q * 4;
    d[0] = make_float2(va.x, vb.x);
    d[1] = make_float2(va.y, vb.y);
    d[2] = make_float2(va.z, vb.z);
    d[3] = make_float2(va.w, vb.w);
  }
  __syncthreads();

  // Radix-3 stage, Ns=1: 4 rows x 256 = 1024 butterflies, 4/thread
  {
    float2 R[4][3]; int ix[4];
#pragma unroll
    for (int t = 0; t < 4; ++t) {
      const int w = tid + t * 256;
      const int row = w >> 8;
      const int j = w & 255;
      const float2* s = buf + row * HN;
      float2 v0 = s[j], v1 = s[j + 256], v2 = s[j + 512];
      float tr = v1.x + v2.x, ti = v1.y + v2.y;
      float ur = v1.x - v2.x, ui = v1.y - v2.y;
      const float cc = -0.5f, sn = -0.8660254037844386f;
      R[t][0] = make_float2(v0.x + tr, v0.y + ti);
      R[t][1] = make_float2(v0.x + cc * tr - sn * ui, v0.y + cc * ti + sn * ur);
      R[t][2] = make_float2(v0.x + cc * tr + sn * ui, v0.y + cc * ti - sn * ur);
      ix[t] = row * HN + 3 * j;
    }
    __syncthreads();
#pragma unroll
    for (int t = 0; t < 4; ++t) {
      buf[ix[t]] = R[t][0]; buf[ix[t] + 1] = R[t][1]; buf[ix[t] + 2] = R[t][2];
    }
    __syncthreads();
  }

  // Radix-4 stages, Ns = 3,12,48,192: 4 rows x 192 = 768 butterflies, 3/thread
  int Ns = 3;
#pragma unroll
  for (int st = 0; st < 4; ++st) {
    const int mult = 64 >> (2 * st);   // T768 index stride: w1 = exp(-2pi i jm/(4Ns))
    float2 V[3][4]; int ix[3];
#pragma unroll
    for (int t = 0; t < 3; ++t) {
      const int w = tid + t * 256;
      const int row = w / 192;
      const int j = w - row * 192;
      const float2* s = buf + row * HN;
      float2 v0 = s[j], v1 = s[j + 192], v2 = s[j + 384], v3 = s[j + 576];
      const int jm = j % Ns;
      float2 w1 = T768[jm * mult];
      float2 w2 = cmul(w1, w1);
      float2 w3 = cmul(w2, w1);
      v1 = cmul(v1, w1); v2 = cmul(v2, w2); v3 = cmul(v3, w3);
      bfly4(v0, v1, v2, v3, V[t][0], V[t][1], V[t][2], V[t][3]);
      ix[t] = row * HN + (j / Ns) * (Ns * 4) + jm;
    }
    __syncthreads();
#pragma unroll
    for (int t = 0; t < 3; ++t) {
      buf[ix[t]] = V[t][0]; buf[ix[t] + Ns] = V[t][1];
      buf[ix[t] + 2 * Ns] = V[t][2]; buf[ix[t] + 3 * Ns] = V[t][3];
    }
    __syncthreads();
    Ns *= 4;
  }

  // Hermitian unpack + transposed store. Each (thread,k) writes a full 64 B line.
  for (int k = tid; k < KP; k += 256) {
    float4 o[4];
    if (k == 0) {
      // Pack the two real planes: slot (b,0,n1) = (Y1[n1][0], Y1[n1][384])
#pragma unroll
      for (int p = 0; p < 4; ++p) {
        float2 z0 = buf[p * HN];
        float2 zh = buf[p * HN + 384];
        o[p] = make_float4(z0.x, zh.x, z0.y, zh.y);
      }
    } else {
      const int km = HN - k;
#pragma unroll
      for (int p = 0; p < 4; ++p) {
        float2 Z = buf[p * HN + k], Zm = buf[p * HN + km];
        o[p] = make_float4(0.5f * (Z.x + Zm.x), 0.5f * (Z.y - Zm.y),
                           0.5f * (Z.y + Zm.y), 0.5f * (Zm.x - Z.x));
      }
    }
    float4* wv = (float4*)(ws + ((size_t)(b * KP + k)) * SN + n0);
    wv[0] = o[0]; wv[1] = o[1]; wv[2] = o[2]; wv[3] = o[3];
  }
}

// ---------------- Pass 2: seq FFT (4096 = 4^6), in-place LDS, table twiddles ----------------
__global__ __launch_bounds__(512, 8)
void fft_seq(float2* __restrict__ ws) {
  __shared__ float2 buf[SN];     // 32 KB
  __shared__ float2 T4[1024];    // 8 KB
  const int tid = threadIdx.x;
  const int blk = blockIdx.x;    // 3072 blocks
  const int b = blk & 7;
  const int k2 = blk >> 3;
  const size_t base = ((size_t)(b * KP + k2)) * SN;

  for (int r = tid; r < 1024; r += 512) {
    float s, c; __sincosf(-PI2 * (float)r * (1.0f / 4096.0f), &s, &c);
    T4[r] = make_float2(c, s);
  }
  const float4* src4 = (const float4*)(ws + base);
  for (int i = tid; i < 2048; i += 512)
    ((float4*)buf)[i] = src4[i];
  __syncthreads();

#pragma unroll
  for (int st = 0; st < 6; ++st) {
    const int Ns = 1 << (2 * st);
    const int sh = 10 - 2 * st;
    float2 V[2][4]; int ix[2];
#pragma unroll
    for (int t = 0; t < 2; ++t) {
      const int j = tid + t * 512;
      float2 v0 = buf[j], v1 = buf[j + 1024], v2 = buf[j + 2048], v3 = buf[j + 3072];
      const int jm = j & (Ns - 1);
      float2 w1 = T4[jm << sh];
      float2 w2 = cmul(w1, w1);
      float2 w3 = cmul(w2, w1);
      v1 = cmul(v1, w1); v2 = cmul(v2, w2); v3 = cmul(v3, w3);
      bfly4(v0, v1, v2, v3, V[t][0], V[t][1], V[t][2], V[t][3]);
      ix[t] = ((j & ~(Ns - 1)) << 2) + jm;
    }
    __syncthreads();
#pragma unroll
    for (int t = 0; t < 2; ++t) {
      buf[ix[t]] = V[t][0]; buf[ix[t] + Ns] = V[t][1];
      buf[ix[t] + 2 * Ns] = V[t][2]; buf[ix[t] + 3 * Ns] = V[t][3];
    }
    __syncthreads();
  }

  float* rowF = (float*)(ws + base);
  if (k2 == 0) {
    // Two real spectra packed: Re P0 -> [0,4096), Re P384 -> [4096,8192)
    for (int i = tid; i < SN; i += 512) {
      const int im = (SN - i) & (SN - 1);
      rowF[i]      = 0.5f * (buf[i].x + buf[im].x);
      rowF[SN + i] = 0.5f * (buf[i].y + buf[im].y);
    }
  } else {
    float4* row4 = (float4*)rowF;
    for (int i = tid; i < 1024; i += 512)
      row4[i] = make_float4(buf[4 * i].x, buf[4 * i + 1].x, buf[4 * i + 2].x, buf[4 * i + 3].x);
  }
}

// ---------------- Pass 3: transpose + Hermitian mirror + col-384 sideband ----------------
__global__ __launch_bounds__(256)
void transpose_mirror(const float* __restrict__ ws, float* __restrict__ out) {
  __shared__ float tile[64][65];
  const int b = blockIdx.z;
  const int k1_0 = blockIdx.x * 64;
  const int k2_0 = blockIdx.y * 64;    // 0..320, exact 6 tiles over [0,384)
  const float* ibF = ws + (size_t)b * KP * (2 * SN);
  float* ob = out + (size_t)b * SN * HN;
  const int t = threadIdx.x;
  const int cx = (t & 15) * 4;
  const int ry = t >> 4;

#pragma unroll
  for (int i = 0; i < 4; ++i) {
    const int k2l = ry + 16 * i;
    float4 v = *(const float4*)(ibF + (size_t)(k2_0 + k2l) * (2 * SN) + k1_0 + cx);
    tile[k2l][cx] = v.x; tile[k2l][cx + 1] = v.y; tile[k2l][cx + 2] = v.z; tile[k2l][cx + 3] = v.w;
  }

  // col-384 sideband: plane-0 row's second half holds Re P384[k1]
  if (blockIdx.y == 0 && t < 64) {
    const float v = ibF[SN + k1_0 + t];
    ob[(size_t)(k1_0 + t) * HN + 384] = v;
  }
  __syncthreads();

#pragma unroll
  for (int i = 0; i < 4; ++i) {
    const int k1l = ry + 16 * i;
    const int k1 = k1_0 + k1l;
    const int k2 = k2_0 + cx;          // multiple of 4, <= 380
    float v0 = tile[cx][k1l], v1 = tile[cx + 1][k1l], v2 = tile[cx + 2][k1l], v3 = tile[cx + 3][k1l];
    *(float4*)(ob + (size_t)k1 * HN + k2) = make_float4(v0, v1, v2, v3);
    // Hermitian mirror: out[-k1][768-k2'] = v(k2'), valid k2' in [1,383]
    const int mr = (SN - k1) & (SN - 1);
    float* mb = ob + (size_t)mr * HN;
    if (k2 > 0) mb[HN - k2] = v0;
    mb[HN - k2 - 1] = v1;
    mb[HN - k2 - 2] = v2;
    mb[HN - k2 - 3] = v3;
  }
}

extern "C" void kernel_launch(void* const* d_in, const int* in_sizes, int n_in,
                              void* d_out, int out_size, void* d_ws, size_t ws_size,
                              hipStream_t stream) {
  const float* x = (const float*)d_in[0];
  float* out = (float*)d_out;
  float2* ws2 = (float2*)d_ws;   // 8*384*4096 float2 = 100.66 MB (same footprint as round-0)

  fft_hidden<<<4096, 256, 0, stream>>>(x, ws2);
  fft_seq<<<3072, 512, 0, stream>>>(ws2);
  transpose_mirror<<<dim3(64, 6, 8), dim3(256), 0, stream>>>((const float*)ws2, out);
}